// Round 12
// baseline (46.527 us; speedup 1.0000x reference)
//
#include <hip/hip_runtime.h>

// Problem constants: B=8192, NJ=14, COL=14, sigma=1, radius=4.
#define NJ    14
#define TILE  196          // 14*14 floats per tile (= 49 float4, 784 B)
#define BLK   128          // 2 waves per block
#define JPB   16           // joints per block: lane(0..15) = tile, wave = half
#define N4    (JPB * 49)   // 784 float4 staged per block (12544 B)

typedef __attribute__((address_space(1))) const void g_void;
typedef __attribute__((address_space(3))) void lds_void;

// exp(-0.5*d*d) with the 9-tap cutoff (|d|<=4), via v_exp_f32.
__device__ __forceinline__ float gtap(int d) {
  const int d2 = d * d;
  const float e = exp2f(-0.72134752044448169f * (float)d2);  // 0.5*log2(e)
  return (d2 <= 16) ? e : 0.0f;
}

// 1-D blurred-impulse response at position p for peak pk, with scipy
// 'reflect' padding folded in. Unnormalized (kernel-sum cancels in g/max).
__device__ __forceinline__ float uresp(int p, int pk) {
  float s = gtap(p - pk);
  if (p <= 3)  s += gtap(p + pk + 1);   // low reflection  (q<0 -> -1-q)
  if (p >= 10) s += gtap(27 - p - pk);  // high reflection (q>13 -> 27-q)
  return s;
}

__device__ __forceinline__ float wave_sum(float x) {
#pragma unroll
  for (int off = 32; off >= 1; off >>= 1) x += __shfl_xor(x, off);
  return x;
}

// Half P of one tile: float4 indices f = 2i + P (49 = 25 + 24).
// All element indices compile-time -> uy/ux stay in registers (rule #20).
// Direct cross accumulation (no rd[14]) keeps live VGPRs low for occupancy.
template<int P>
__device__ __forceinline__ void accum_part(const float4* __restrict__ hp,
    const float (&uy)[14], const float (&ux)[14],
    float& bm, int& bi, float& sh2, float& cross, float& q0)
{
  const int NI = (P == 0) ? 25 : 24;
#pragma unroll
  for (int i = 0; i < NI; ++i) {
    const int f = 2 * i + P;
    const float4 q = hp[f];            // ds_read_b128
    const float qa[4] = {q.x, q.y, q.z, q.w};
#pragma unroll
    for (int c = 0; c < 4; ++c) {
      const int idx = 4 * f + c;
      const int y = idx / 14;
      const int x = idx - 14 * y;            // compile-time
      const float hv = qa[c];
      if (hv > bm) { bm = hv; bi = idx; }    // first-index within half
      sh2 = fmaf(hv, hv, sh2);
      if (y == 0) q0 = fmaf(hv, hv, q0);     // row-0 energy (invis fixup)
      cross = fmaf(hv, uy[y] * ux[x], cross);
    }
  }
}

__global__ __launch_bounds__(BLK, 4) void joint_kernel(
    const float* __restrict__ o, const float* __restrict__ h,
    const float* __restrict__ t, const float* __restrict__ v,
    float2* __restrict__ part)
{
  // 12544B stage buffer; aliased for the cross-wave combine after a barrier.
  __shared__ __align__(16) float lds[N4 * 4];
  __shared__ float rs[2], rn[2];   // dedicated (tiny)

  const int tid  = threadIdx.x;
  const int lane = tid & 63;
  const int wid  = tid >> 6;                 // 0 or 1
  const int jl   = lane & 15;                // joint slot 0..15
  const int jg   = blockIdx.x * JPB + jl;    // grid exact: 7168*16 = 114688

  // ---- coalesced global->LDS stage of this block's 16 tiles ----
  const float* gbase = h + (size_t)blockIdx.x * JPB * TILE;
#pragma unroll
  for (int i = 0; i < 7; ++i) {
    const int idx = i * BLK + tid;
    if (idx < N4) {
      __builtin_amdgcn_global_load_lds(
          (g_void*)(gbase + (size_t)idx * 4),       // per-lane global src
          (lds_void*)&lds[idx * 4],                 // uniform base + lane*16
          16, 0, 0);
    }
  }

  // ---- overlap: analytic 1-D responses while loads fly ----
  float uy[14], ux[14];
  const float2 tv = ((const float2*)t)[jg];
  const int xi = min(max((int)(tv.x * 14.0f), 0), 13);
  const int yi = min(max((int)(tv.y * 14.0f), 0), 13);
#pragma unroll
  for (int p = 0; p < 14; ++p) { uy[p] = uresp(p, yi); ux[p] = uresp(p, xi); }

  asm volatile("s_waitcnt vmcnt(0)" ::: "memory");
  __syncthreads();

  // ---- half-tile pass: lanes 0..15 own tiles, wave = half (divergence-free
  // across active lanes; lanes 16..63 idle through this short phase) ----
  float bm = -3.0e38f; int bi = 0;
  float sh2 = 0.0f, cross = 0.0f, q0 = 0.0f;
  if (lane < 16) {
    const float4* hp = (const float4*)&lds[jl * TILE];
    if (wid == 0) accum_part<0>(hp, uy, ux, bm, bi, sh2, cross, q0);
    else          accum_part<1>(hp, uy, ux, bm, bi, sh2, cross, q0);
  }

  __syncthreads();   // both waves done READING tiles; safe to alias LDS
  float* red = lds;  // 5 fields x [2 waves][16 joints] = 640B, aliased
  if (lane < 16) {
    red[0 * 32 + wid * 16 + jl] = bm;
    ((int*)lds)[1 * 32 + wid * 16 + jl] = bi;
    red[2 * 32 + wid * 16 + jl] = sh2;
    red[3 * 32 + wid * 16 + jl] = cross;
    red[4 * 32 + wid * 16 + jl] = q0;
  }
  __syncthreads();

  // ---- 2-way parallel epilogue: wave w handles joints [8w, 8w+8).
  // Lane L (<16) of each wave holds uy/ux for joint L in registers.
  float s_acc = 0.0f, n_acc = 0.0f;
  if (lane < 16 && (lane >> 3) == wid) {
    // combine the two halves for this lane's joint (global first-index)
    float Bm = red[0 * 32 + jl];       int Bi = ((int*)lds)[1 * 32 + jl];
    {
      const float m = red[0 * 32 + 16 + jl];
      const int   i = ((int*)lds)[1 * 32 + 16 + jl];
      if (m > Bm || (m == Bm && i < Bi)) { Bm = m; Bi = i; }
    }
    const float S2 = red[2 * 32 + jl] + red[2 * 32 + 16 + jl];
    const float Cr = red[3 * 32 + jl] + red[3 * 32 + 16 + jl];
    const float Q0 = red[4 * 32 + jl] + red[4 * 32 + 16 + jl];

    const float2 vv = ((const float2*)v)[jg];
    const bool vis = ((int)vv.x) == 1;

    float Sy2 = 0.0f, Sx2 = 0.0f;
#pragma unroll
    for (int p = 0; p < 14; ++p) {
      Sy2 = fmaf(uy[p], uy[p], Sy2);
      Sx2 = fmaf(ux[p], ux[p], Sx2);
    }
    const float maxy = 1.0f + gtap(2 * yi + 1) + gtap(27 - 2 * yi);
    const float maxx = 1.0f + gtap(2 * xi + 1) + gtap(27 - 2 * xi);
    const float inv = vis ? (1.0f / (maxy * maxx)) : 0.0f;

    // sum(h-tt)^2 = S2 - 2*inv*Cr + inv^2*Sy2*Sx2 ; row0 zeroed if invis
    float s = S2 - 2.0f * inv * Cr + inv * inv * Sy2 * Sx2;
    if (!vis) s -= Q0;

    // ---- coordinate loss (argmax-dependent gather, stays global) ----
    const int b = jg / NJ;
    const int j = jg - b * NJ;
    const int yC = Bi / 14;
    const int xC = Bi - 14 * yC;
    const size_t ob = ((size_t)b * (2 * NJ) + j) * TILE + (size_t)Bi;
    const float ox = o[ob];
    const float oy = o[ob + (size_t)NJ * TILE];
    const bool cond = Bm > 0.5f;
    const float sc = 1.0f / 14.0f;
    const float px = cond ? (ox + (float)xC) * sc : 0.0f;
    const float py = cond ? (oy + (float)yC) * sc : 0.0f;
    const float d0 = (px - tv.x) * vv.x;
    const float d1 = (py - tv.y) * vv.y;
    s += d0 * d0 + d1 * d1;

    s_acc = s;
    n_acc = vv.x + vv.y;
  }

  // ---- per-wave deterministic sum (inactive lanes contribute 0) ----
  s_acc = wave_sum(s_acc);
  n_acc = wave_sum(n_acc);
  if (lane == 0) { rs[wid] = s_acc; rn[wid] = n_acc; }
  __syncthreads();
  if (tid == 0) part[blockIdx.x] = make_float2(rs[0] + rs[1], rn[0] + rn[1]);
}

#define FBLK 1024
__global__ __launch_bounds__(FBLK) void finalize_kernel(
    const float2* __restrict__ part, float* __restrict__ out, int nblocks)
{
  float s = 0.0f, n = 0.0f;
  for (int i = threadIdx.x; i < nblocks; i += FBLK) {   // 7 coalesced rounds
    const float2 p = part[i];
    s += p.x;
    n += p.y;
  }
  s = wave_sum(s);
  n = wave_sum(n);
  __shared__ float rs[16], rn[16];
  const int lane = threadIdx.x & 63, wid = threadIdx.x >> 6;
  if (lane == 0) { rs[wid] = s; rn[wid] = n; }
  __syncthreads();
  if (threadIdx.x == 0) {
    float S = 0.0f, N = 0.0f;
#pragma unroll
    for (int i = 0; i < 16; ++i) { S += rs[i]; N += rn[i]; }
    out[0] = S / (0.5f * N);   // (d1_sum + d2_sum) / N1, N1 = sum(v)/2
  }
}

extern "C" void kernel_launch(void* const* d_in, const int* in_sizes, int n_in,
                              void* d_out, int out_size, void* d_ws, size_t ws_size,
                              hipStream_t stream)
{
  const float* o = (const float*)d_in[0];  // [B, 2*NJ, 14, 14]
  const float* h = (const float*)d_in[1];  // [B, NJ, 14, 14]
  const float* t = (const float*)d_in[2];  // [B, NJ, 2]
  const float* v = (const float*)d_in[3];  // [B, NJ, 2]
  const int njoint = in_sizes[1] / TILE;   // B*NJ = 114688 (= 7168*16 exact)
  const int nblocks = njoint / JPB;        // 7168

  float2* part = (float2*)d_ws;  // nblocks float2 = 57344B, rewritten each call
  joint_kernel<<<nblocks, BLK, 0, stream>>>(o, h, t, v, part);
  finalize_kernel<<<1, FBLK, 0, stream>>>(part, (float*)d_out, nblocks);
}

// Round 13
// 31.315 us; speedup vs baseline: 1.4858x; 1.4858x over previous
//
#include <hip/hip_runtime.h>

// Problem constants: B=8192, NJ=14, COL=14, sigma=1, radius=4.
#define NJ    14
#define TILE  196          // 14*14 floats per tile (= 49 float4, 784 B)
#define BLK   256
#define JPB   64           // joints per block: lane = tile, wave = quarter
#define STAGE_DW (JPB * TILE)   // 12544 dwords = 50176 B staged per block

typedef __attribute__((address_space(1))) const void g_void;
typedef __attribute__((address_space(3))) void lds_void;

// exp(-0.5*d*d) with the 9-tap cutoff (|d|<=4), via v_exp_f32.
__device__ __forceinline__ float gtap(int d) {
  const int d2 = d * d;
  const float e = exp2f(-0.72134752044448169f * (float)d2);  // 0.5*log2(e)
  return (d2 <= 16) ? e : 0.0f;
}

// 1-D blurred-impulse response at position p for peak pk, with scipy
// 'reflect' padding folded in. Unnormalized (kernel-sum cancels in g/max).
__device__ __forceinline__ float uresp(int p, int pk) {
  float s = gtap(p - pk);
  if (p <= 3)  s += gtap(p + pk + 1);   // low reflection  (q<0 -> -1-q)
  if (p >= 10) s += gtap(27 - p - pk);  // high reflection (q>13 -> 27-q)
  return s;
}

__device__ __forceinline__ float wave_sum(float x) {
#pragma unroll
  for (int off = 32; off >= 1; off >>= 1) x += __shfl_xor(x, off);
  return x;
}

// Quarter K of one tile: float4 indices f = 4i + K (49 = 13+12+12+12).
// rowdot decomposition: rd[y] += h*ux[x] (1 fma/elem, compile-time y/x);
// cross = sum_y uy[y]*rd[y] folded at the end (14 fmas). All indices
// compile-time -> uy/ux/rd stay in registers (rule #20).
template<int K>
__device__ __forceinline__ void accum_part(const float4* __restrict__ hp,
    const float (&uy)[14], const float (&ux)[14],
    float& bm, int& bi, float& sh2, float& cross, float& q0)
{
  float rd[14] = {0,0,0,0,0,0,0,0,0,0,0,0,0,0};
  const int NI = (K == 0) ? 13 : 12;
#pragma unroll
  for (int i = 0; i < NI; ++i) {
    const int f = 4 * i + K;
    const float4 q = hp[f];            // ds_read_b128, stride 784B
    const float qa[4] = {q.x, q.y, q.z, q.w};
#pragma unroll
    for (int c = 0; c < 4; ++c) {
      const int idx = 4 * f + c;
      const int y = idx / 14;
      const int x = idx - 14 * y;            // compile-time
      const float hv = qa[c];
      if (hv > bm) { bm = hv; bi = idx; }    // first-index within quarter
      sh2 = fmaf(hv, hv, sh2);
      if (y == 0) q0 = fmaf(hv, hv, q0);     // row-0 energy (invis fixup)
      rd[y] = fmaf(hv, ux[x], rd[y]);
    }
  }
#pragma unroll
  for (int y = 0; y < 14; ++y) cross = fmaf(uy[y], rd[y], cross);
}

__global__ __launch_bounds__(BLK, 3) void joint_kernel(
    const float* __restrict__ o, const float* __restrict__ h,
    const float* __restrict__ t, const float* __restrict__ v,
    float2* __restrict__ part)
{
  // 50176B stage buffer; reused (aliased) for the cross-wave reduction arrays.
  __shared__ __align__(16) float lds[STAGE_DW];
  __shared__ float rs[4], rn[4];   // dedicated (NOT aliased): live during epilogue

  const int tid  = threadIdx.x;
  const int lane = tid & 63;
  const int wid  = tid >> 6;
  const int jg   = blockIdx.x * JPB + lane;   // grid exact: 1792*64 = 114688

  // ---- phase stagger: the 3 initially co-resident blocks on a CU are
  // blockIdx, +256, +512. Delay slots 1/2 by ~2/4 us so the 3 pipelines'
  // stage/compute windows interleave instead of convoying; later blocks
  // inherit the freed slot's phase, so the stagger self-sustains.
  {
    const int key = (blockIdx.x >> 8) % 3;
    for (int i = 0; i < key * 5; ++i) __builtin_amdgcn_s_sleep(15);
  }

  // ---- per-joint scalars issued BEFORE the stage stream (overlap) ----
  const float2 tv = ((const float2*)t)[jg];
  const float2 vv = ((const float2*)v)[jg];

  // ---- coalesced global->LDS stage of this block's 64 tiles ----
  // 3136 float4 = 12*256 + 64: 12 unconditional rounds + 1 wave-0 round.
  const float* gbase = h + (size_t)blockIdx.x * JPB * TILE;
#pragma unroll
  for (int i = 0; i < 12; ++i) {
    const int idx = i * BLK + tid;
    __builtin_amdgcn_global_load_lds(
        (g_void*)(gbase + (size_t)idx * 4),       // per-lane global src
        (lds_void*)&lds[idx * 4],                 // uniform base + lane*16
        16, 0, 0);
  }
  if (wid == 0) {
    const int idx = 12 * BLK + lane;
    __builtin_amdgcn_global_load_lds(
        (g_void*)(gbase + (size_t)idx * 4),
        (lds_void*)&lds[idx * 4], 16, 0, 0);
  }

  // ---- overlap: analytic 1-D responses while loads fly ----
  float uy[14], ux[14];
  const int xi = min(max((int)(tv.x * 14.0f), 0), 13);
  const int yi = min(max((int)(tv.y * 14.0f), 0), 13);
#pragma unroll
  for (int p = 0; p < 14; ++p) { uy[p] = uresp(p, yi); ux[p] = uresp(p, xi); }

  asm volatile("s_waitcnt vmcnt(0)" ::: "memory");
  __syncthreads();

  // ---- per-wave quarter pass over this lane's tile (divergence-free) ----
  float bm = -3.0e38f; int bi = 0;
  float sh2 = 0.0f, cross = 0.0f, q0 = 0.0f;
  {
    const float4* hp = (const float4*)&lds[lane * TILE];
    switch (wid) {   // wave-uniform branch: no lane divergence
      case 0: accum_part<0>(hp, uy, ux, bm, bi, sh2, cross, q0); break;
      case 1: accum_part<1>(hp, uy, ux, bm, bi, sh2, cross, q0); break;
      case 2: accum_part<2>(hp, uy, ux, bm, bi, sh2, cross, q0); break;
      default: accum_part<3>(hp, uy, ux, bm, bi, sh2, cross, q0); break;
    }
  }

  __syncthreads();   // all waves done READING tiles; safe to alias LDS
  float* red = lds;  // 5 arrays x 256 x 4B = 5120B, aliased into stage buffer
  red[0 * BLK + tid] = bm;
  ((int*)lds)[1 * BLK + tid] = bi;
  red[2 * BLK + tid] = sh2;
  red[3 * BLK + tid] = cross;
  red[4 * BLK + tid] = q0;
  __syncthreads();

  // ---- 4-way parallel epilogue: wave w handles joints [16w, 16w+16).
  // Lane L of EVERY wave holds uy/ux for joint L in registers, so wave w
  // activates lanes 16w..16w+15 (their registers match those joints).
  float s_acc = 0.0f, n_acc = 0.0f;
  if ((lane >> 4) == wid) {
    // ---- combine the 4 quarters for this lane's joint ----
    float Bm = red[lane]; int Bi = ((int*)lds)[BLK + lane];
    float S2 = red[2 * BLK + lane], Cr = red[3 * BLK + lane], Q0 = red[4 * BLK + lane];
#pragma unroll
    for (int w = 1; w < 4; ++w) {
      const float m = red[w * 64 + lane];
      const int   i = ((int*)lds)[BLK + w * 64 + lane];
      if (m > Bm || (m == Bm && i < Bi)) { Bm = m; Bi = i; }  // global first-index
      S2 += red[2 * BLK + w * 64 + lane];
      Cr += red[3 * BLK + w * 64 + lane];
      Q0 += red[4 * BLK + w * 64 + lane];
    }

    const bool vis = ((int)vv.x) == 1;

    float Sy2 = 0.0f, Sx2 = 0.0f;
#pragma unroll
    for (int p = 0; p < 14; ++p) {
      Sy2 = fmaf(uy[p], uy[p], Sy2);
      Sx2 = fmaf(ux[p], ux[p], Sx2);
    }
    const float maxy = 1.0f + gtap(2 * yi + 1) + gtap(27 - 2 * yi);
    const float maxx = 1.0f + gtap(2 * xi + 1) + gtap(27 - 2 * xi);
    const float inv = vis ? (1.0f / (maxy * maxx)) : 0.0f;

    // sum(h-tt)^2 = S2 - 2*inv*Cr + inv^2*Sy2*Sx2 ; row0 zeroed if invis
    float s = S2 - 2.0f * inv * Cr + inv * inv * Sy2 * Sx2;
    if (!vis) s -= Q0;

    // ---- coordinate loss (argmax-dependent gather, stays global) ----
    const int b = jg / NJ;
    const int j = jg - b * NJ;
    const int yC = Bi / 14;
    const int xC = Bi - 14 * yC;
    const size_t ob = ((size_t)b * (2 * NJ) + j) * TILE + (size_t)Bi;
    const float ox = o[ob];
    const float oy = o[ob + (size_t)NJ * TILE];
    const bool cond = Bm > 0.5f;
    const float sc = 1.0f / 14.0f;
    const float px = cond ? (ox + (float)xC) * sc : 0.0f;
    const float py = cond ? (oy + (float)yC) * sc : 0.0f;
    const float d0 = (px - tv.x) * vv.x;
    const float d1 = (py - tv.y) * vv.y;
    s += d0 * d0 + d1 * d1;

    s_acc = s;
    n_acc = vv.x + vv.y;
  }

  // ---- per-wave deterministic sum (inactive lanes contribute 0) ----
  s_acc = wave_sum(s_acc);
  n_acc = wave_sum(n_acc);
  if (lane == 0) { rs[wid] = s_acc; rn[wid] = n_acc; }
  __syncthreads();
  if (tid == 0) {
    const float S = rs[0] + rs[1] + rs[2] + rs[3];
    const float N = rn[0] + rn[1] + rn[2] + rn[3];
    part[blockIdx.x] = make_float2(S, N);
  }
}

#define FBLK 1024
__global__ __launch_bounds__(FBLK) void finalize_kernel(
    const float2* __restrict__ part, float* __restrict__ out, int nblocks)
{
  float s = 0.0f, n = 0.0f;
  for (int i = threadIdx.x; i < nblocks; i += FBLK) {   // 2 coalesced rounds
    const float2 p = part[i];
    s += p.x;
    n += p.y;
  }
  s = wave_sum(s);
  n = wave_sum(n);
  __shared__ float rs[16], rn[16];
  const int lane = threadIdx.x & 63, wid = threadIdx.x >> 6;
  if (lane == 0) { rs[wid] = s; rn[wid] = n; }
  __syncthreads();
  if (threadIdx.x == 0) {
    float S = 0.0f, N = 0.0f;
#pragma unroll
    for (int i = 0; i < 16; ++i) { S += rs[i]; N += rn[i]; }
    out[0] = S / (0.5f * N);   // (d1_sum + d2_sum) / N1, N1 = sum(v)/2
  }
}

extern "C" void kernel_launch(void* const* d_in, const int* in_sizes, int n_in,
                              void* d_out, int out_size, void* d_ws, size_t ws_size,
                              hipStream_t stream)
{
  const float* o = (const float*)d_in[0];  // [B, 2*NJ, 14, 14]
  const float* h = (const float*)d_in[1];  // [B, NJ, 14, 14]
  const float* t = (const float*)d_in[2];  // [B, NJ, 2]
  const float* v = (const float*)d_in[3];  // [B, NJ, 2]
  const int njoint = in_sizes[1] / TILE;   // B*NJ = 114688 (= 1792*64 exact)
  const int nblocks = njoint / JPB;        // 1792

  float2* part = (float2*)d_ws;  // nblocks float2 = 14336B, rewritten each call
  joint_kernel<<<nblocks, BLK, 0, stream>>>(o, h, t, v, part);
  finalize_kernel<<<1, FBLK, 0, stream>>>(part, (float*)d_out, nblocks);
}

// Round 14
// 28.708 us; speedup vs baseline: 1.6207x; 1.0908x over previous
//
#include <hip/hip_runtime.h>

// Problem constants: B=8192, NJ=14, COL=14, sigma=1, radius=4.
#define NJ    14
#define TILE  196          // 14*14 floats per tile (= 49 float4, 784 B)
#define BLK   256
#define JPB   64           // joints per block: lane = tile, wave = quarter
#define STAGE_DW (JPB * TILE)   // 12544 dwords = 50176 B staged per block

typedef __attribute__((address_space(1))) const void g_void;
typedef __attribute__((address_space(3))) void lds_void;

// exp(-0.5*d*d) with the 9-tap cutoff (|d|<=4), via v_exp_f32.
__device__ __forceinline__ float gtap(int d) {
  const int d2 = d * d;
  const float e = exp2f(-0.72134752044448169f * (float)d2);  // 0.5*log2(e)
  return (d2 <= 16) ? e : 0.0f;
}

// 1-D blurred-impulse response at position p for peak pk, with scipy
// 'reflect' padding folded in. Unnormalized (kernel-sum cancels in g/max).
__device__ __forceinline__ float uresp(int p, int pk) {
  float s = gtap(p - pk);
  if (p <= 3)  s += gtap(p + pk + 1);   // low reflection  (q<0 -> -1-q)
  if (p >= 10) s += gtap(27 - p - pk);  // high reflection (q>13 -> 27-q)
  return s;
}

__device__ __forceinline__ float wave_sum(float x) {
#pragma unroll
  for (int off = 32; off >= 1; off >>= 1) x += __shfl_xor(x, off);
  return x;
}

// Quarter K of one tile: float4 indices f = 4i + K (49 = 13+12+12+12).
// rowdot decomposition: rd[y] += h*ux[x] (1 fma/elem, compile-time y/x);
// cross = sum_y uy[y]*rd[y] folded at the end (14 fmas). All indices
// compile-time -> uy/ux/rd stay in registers (rule #20).
template<int K>
__device__ __forceinline__ void accum_part(const float4* __restrict__ hp,
    const float (&uy)[14], const float (&ux)[14],
    float& bm, int& bi, float& sh2, float& cross, float& q0)
{
  float rd[14] = {0,0,0,0,0,0,0,0,0,0,0,0,0,0};
  const int NI = (K == 0) ? 13 : 12;
#pragma unroll
  for (int i = 0; i < NI; ++i) {
    const int f = 4 * i + K;
    const float4 q = hp[f];            // ds_read_b128, stride 784B (bank-clean)
    const float qa[4] = {q.x, q.y, q.z, q.w};
#pragma unroll
    for (int c = 0; c < 4; ++c) {
      const int idx = 4 * f + c;
      const int y = idx / 14;
      const int x = idx - 14 * y;            // compile-time
      const float hv = qa[c];
      if (hv > bm) { bm = hv; bi = idx; }    // first-index within quarter
      sh2 = fmaf(hv, hv, sh2);
      if (y == 0) q0 = fmaf(hv, hv, q0);     // row-0 energy (invis fixup)
      rd[y] = fmaf(hv, ux[x], rd[y]);
    }
  }
#pragma unroll
  for (int y = 0; y < 14; ++y) cross = fmaf(uy[y], rd[y], cross);
}

__global__ __launch_bounds__(BLK, 3) void joint_kernel(
    const float* __restrict__ o, const float* __restrict__ h,
    const float* __restrict__ t, const float* __restrict__ v,
    float2* __restrict__ part)
{
  // 50176B stage buffer; reused (aliased) for the cross-wave reduction arrays.
  __shared__ __align__(16) float lds[STAGE_DW];
  __shared__ float rs[4], rn[4];   // dedicated (NOT aliased): live during epilogue

  const int tid  = threadIdx.x;
  const int lane = tid & 63;
  const int wid  = tid >> 6;
  const int jg   = blockIdx.x * JPB + lane;   // grid exact: 1792*64 = 114688

  // ---- coalesced global->LDS stage of this block's 64 tiles ----
  const float* gbase = h + (size_t)blockIdx.x * JPB * TILE;
#pragma unroll
  for (int i = 0; i < 13; ++i) {
    const int idx = i * BLK + tid;
    if (idx < JPB * 49) {
      __builtin_amdgcn_global_load_lds(
          (g_void*)(gbase + (size_t)idx * 4),       // per-lane global src
          (lds_void*)&lds[idx * 4],                 // uniform base + lane*16
          16, 0, 0);
    }
  }

  // ---- overlap: analytic 1-D responses while loads fly ----
  float uy[14], ux[14];
  const float2 tv = ((const float2*)t)[jg];
  const int xi = min(max((int)(tv.x * 14.0f), 0), 13);
  const int yi = min(max((int)(tv.y * 14.0f), 0), 13);
#pragma unroll
  for (int p = 0; p < 14; ++p) { uy[p] = uresp(p, yi); ux[p] = uresp(p, xi); }

  asm volatile("s_waitcnt vmcnt(0)" ::: "memory");
  __syncthreads();

  // ---- per-wave quarter pass over this lane's tile (divergence-free) ----
  float bm = -3.0e38f; int bi = 0;
  float sh2 = 0.0f, cross = 0.0f, q0 = 0.0f;
  {
    const float4* hp = (const float4*)&lds[lane * TILE];
    switch (wid) {   // wave-uniform branch: no lane divergence
      case 0: accum_part<0>(hp, uy, ux, bm, bi, sh2, cross, q0); break;
      case 1: accum_part<1>(hp, uy, ux, bm, bi, sh2, cross, q0); break;
      case 2: accum_part<2>(hp, uy, ux, bm, bi, sh2, cross, q0); break;
      default: accum_part<3>(hp, uy, ux, bm, bi, sh2, cross, q0); break;
    }
  }

  __syncthreads();   // all waves done READING tiles; safe to alias LDS
  float* red = lds;  // 5 arrays x 256 x 4B = 5120B, aliased into stage buffer
  red[0 * BLK + tid] = bm;
  ((int*)lds)[1 * BLK + tid] = bi;
  red[2 * BLK + tid] = sh2;
  red[3 * BLK + tid] = cross;
  red[4 * BLK + tid] = q0;
  __syncthreads();

  // ---- 4-way parallel epilogue: wave w handles joints [16w, 16w+16).
  // Lane L of EVERY wave holds uy/ux for joint L in registers, so wave w
  // activates lanes 16w..16w+15 (their registers match those joints).
  float s_acc = 0.0f, n_acc = 0.0f;
  if ((lane >> 4) == wid) {
    // ---- combine the 4 quarters for this lane's joint ----
    float Bm = red[lane]; int Bi = ((int*)lds)[BLK + lane];
    float S2 = red[2 * BLK + lane], Cr = red[3 * BLK + lane], Q0 = red[4 * BLK + lane];
#pragma unroll
    for (int w = 1; w < 4; ++w) {
      const float m = red[w * 64 + lane];
      const int   i = ((int*)lds)[BLK + w * 64 + lane];
      if (m > Bm || (m == Bm && i < Bi)) { Bm = m; Bi = i; }  // global first-index
      S2 += red[2 * BLK + w * 64 + lane];
      Cr += red[3 * BLK + w * 64 + lane];
      Q0 += red[4 * BLK + w * 64 + lane];
    }

    const float2 vv = ((const float2*)v)[jg];
    const bool vis = ((int)vv.x) == 1;

    float Sy2 = 0.0f, Sx2 = 0.0f;
#pragma unroll
    for (int p = 0; p < 14; ++p) {
      Sy2 = fmaf(uy[p], uy[p], Sy2);
      Sx2 = fmaf(ux[p], ux[p], Sx2);
    }
    const float maxy = 1.0f + gtap(2 * yi + 1) + gtap(27 - 2 * yi);
    const float maxx = 1.0f + gtap(2 * xi + 1) + gtap(27 - 2 * xi);
    const float inv = vis ? (1.0f / (maxy * maxx)) : 0.0f;

    // sum(h-tt)^2 = S2 - 2*inv*Cr + inv^2*Sy2*Sx2 ; row0 zeroed if invis
    float s = S2 - 2.0f * inv * Cr + inv * inv * Sy2 * Sx2;
    if (!vis) s -= Q0;

    // ---- coordinate loss (argmax-dependent gather, stays global) ----
    const int b = jg / NJ;
    const int j = jg - b * NJ;
    const int yC = Bi / 14;
    const int xC = Bi - 14 * yC;
    const size_t ob = ((size_t)b * (2 * NJ) + j) * TILE + (size_t)Bi;
    const float ox = o[ob];
    const float oy = o[ob + (size_t)NJ * TILE];
    const bool cond = Bm > 0.5f;
    const float sc = 1.0f / 14.0f;
    const float px = cond ? (ox + (float)xC) * sc : 0.0f;
    const float py = cond ? (oy + (float)yC) * sc : 0.0f;
    const float d0 = (px - tv.x) * vv.x;
    const float d1 = (py - tv.y) * vv.y;
    s += d0 * d0 + d1 * d1;

    s_acc = s;
    n_acc = vv.x + vv.y;
  }

  // ---- per-wave deterministic sum (inactive lanes contribute 0) ----
  s_acc = wave_sum(s_acc);
  n_acc = wave_sum(n_acc);
  if (lane == 0) { rs[wid] = s_acc; rn[wid] = n_acc; }
  __syncthreads();
  if (tid == 0) {
    const float S = rs[0] + rs[1] + rs[2] + rs[3];
    const float N = rn[0] + rn[1] + rn[2] + rn[3];
    part[blockIdx.x] = make_float2(S, N);
  }
}

#define FBLK 1024
__global__ __launch_bounds__(FBLK) void finalize_kernel(
    const float2* __restrict__ part, float* __restrict__ out, int nblocks)
{
  float s = 0.0f, n = 0.0f;
  for (int i = threadIdx.x; i < nblocks; i += FBLK) {   // 2 coalesced rounds
    const float2 p = part[i];
    s += p.x;
    n += p.y;
  }
  s = wave_sum(s);
  n = wave_sum(n);
  __shared__ float rs[16], rn[16];
  const int lane = threadIdx.x & 63, wid = threadIdx.x >> 6;
  if (lane == 0) { rs[wid] = s; rn[wid] = n; }
  __syncthreads();
  if (threadIdx.x == 0) {
    float S = 0.0f, N = 0.0f;
#pragma unroll
    for (int i = 0; i < 16; ++i) { S += rs[i]; N += rn[i]; }
    out[0] = S / (0.5f * N);   // (d1_sum + d2_sum) / N1, N1 = sum(v)/2
  }
}

extern "C" void kernel_launch(void* const* d_in, const int* in_sizes, int n_in,
                              void* d_out, int out_size, void* d_ws, size_t ws_size,
                              hipStream_t stream)
{
  const float* o = (const float*)d_in[0];  // [B, 2*NJ, 14, 14]
  const float* h = (const float*)d_in[1];  // [B, NJ, 14, 14]
  const float* t = (const float*)d_in[2];  // [B, NJ, 2]
  const float* v = (const float*)d_in[3];  // [B, NJ, 2]
  const int njoint = in_sizes[1] / TILE;   // B*NJ = 114688 (= 1792*64 exact)
  const int nblocks = njoint / JPB;        // 1792

  float2* part = (float2*)d_ws;  // nblocks float2 = 14336B, rewritten each call
  joint_kernel<<<nblocks, BLK, 0, stream>>>(o, h, t, v, part);
  finalize_kernel<<<1, FBLK, 0, stream>>>(part, (float*)d_out, nblocks);
}